// Round 1
// baseline (2062.587 us; speedup 1.0000x reference)
//
#include <hip/hip_runtime.h>
#include <math.h>

typedef unsigned short u16;
typedef unsigned int   u32;

#define H_    768
#define FF_   3072
#define L_    2
#define B_    64
#define S_    128
#define SP1   129
#define NROWS (B_*SP1)     /* 8256  */
#define M_    (NROWS*3)    /* 24768 */
#define MPAD  24832        /* 194*128 */
#define MT_   (MPAD/128)   /* 194 */

typedef __attribute__((ext_vector_type(8))) short s16x8;
typedef __attribute__((ext_vector_type(4))) float f32x4;

__device__ __forceinline__ float bf2f(u16 u){ union{u32 i; float f;} c; c.i=((u32)u)<<16; return c.f; }
__device__ __forceinline__ u16 f2bf(float x){ union{float f; u32 i;} c; c.f=x; u32 r=c.i+0x7fffu+((c.i>>16)&1u); return (u16)(r>>16); }

__device__ __forceinline__ void bf4u(uint2 u, float* v){
  v[0]=bf2f((u16)(u.x&0xffffu)); v[1]=bf2f((u16)(u.x>>16));
  v[2]=bf2f((u16)(u.y&0xffffu)); v[3]=bf2f((u16)(u.y>>16));
}
__device__ __forceinline__ uint2 fpack4(const float* v){
  u32 lo=(u32)f2bf(v[0]) | ((u32)f2bf(v[1])<<16);
  u32 hi=(u32)f2bf(v[2]) | ((u32)f2bf(v[3])<<16);
  return make_uint2(lo,hi);
}
__device__ __forceinline__ float wredf(float v){
  #pragma unroll
  for (int o=32;o;o>>=1) v += __shfl_xor(v,o,64);
  return v;
}

typedef const __attribute__((address_space(1))) void* gas1_t;
typedef __attribute__((address_space(3))) void*       las3_t;
__device__ __forceinline__ void gload16(const void* g, void* l){
  __builtin_amdgcn_global_load_lds((gas1_t)g, (las3_t)l, 16, 0, 0);
}

/* ---------------- weight transpose + f32->bf16 convert ---------------- */
struct TP9 { const float* s[9]; u16* d[9]; };

__global__ __launch_bounds__(256) void tconv_k(TP9 P, int Rr, int Cc){
  __shared__ u16 tle[32][33];
  const float* src = P.s[blockIdx.z];
  u16* dst = P.d[blockIdx.z];
  int c0 = blockIdx.x*32, r0 = blockIdx.y*32;
  int tx = threadIdx.x&31, ty = threadIdx.x>>5;
  #pragma unroll
  for (int i=0;i<32;i+=8) tle[ty+i][tx] = f2bf(src[(size_t)(r0+ty+i)*Cc + (c0+tx)]);
  __syncthreads();
  #pragma unroll
  for (int i=0;i<32;i+=8) dst[(size_t)(c0+ty+i)*Rr + (r0+tx)] = tle[tx][ty+i];
}

/* ---------------- embedding gather + LN (wave per token row) ---------------- */
__global__ __launch_bounds__(256) void embed_k(const int* __restrict__ ids, const float* __restrict__ wemb,
    const float* __restrict__ pe3, const float* __restrict__ te, const float* __restrict__ gg,
    const float* __restrict__ bb, u16* __restrict__ x)
{
  int m = (int)((blockIdx.x*256u + threadIdx.x)>>6);
  int lane = threadIdx.x&63;
  size_t base = (size_t)m*H_;
  if (m >= M_){ /* MPAD padding rows -> zeros (keeps all GEMM tiles finite/benign) */
    #pragma unroll
    for (int k3=0;k3<3;k3++){ int col=lane*4+k3*256; *(uint2*)&x[base+col]=make_uint2(0u,0u); }
    return;
  }
  int n = m/3, j = m - n*3;
  int bi = n/SP1, sp = n - bi*SP1;
  int id = 0;
  if (sp < S_){
    int s2 = sp + j - 1;               /* j=0:prev, j=1:center, j=2:next */
    if (s2 >= 0 && s2 < S_) id = ids[bi*S_ + s2];
  }                                     /* sp==128 (padded row): id stays 0 like reference */
  const float* wr = wemb + (size_t)id*H_;
  const float* pr = pe3 + j*H_;
  float vals[12]; float s=0.f, sq=0.f;
  #pragma unroll
  for (int k3=0;k3<3;k3++){
    int col = lane*4 + k3*256;
    float4 wv = *(const float4*)(wr+col);
    float4 pv = *(const float4*)(pr+col);
    float4 tv = *(const float4*)(te+col);
    float a0=wv.x+pv.x+tv.x, a1=wv.y+pv.y+tv.y, a2=wv.z+pv.z+tv.z, a3=wv.w+pv.w+tv.w;
    vals[k3*4+0]=a0; vals[k3*4+1]=a1; vals[k3*4+2]=a2; vals[k3*4+3]=a3;
    s += a0+a1+a2+a3; sq += a0*a0+a1*a1+a2*a2+a3*a3;
  }
  s = wredf(s); sq = wredf(sq);
  float mean = s*(1.f/H_);
  float var  = sq*(1.f/H_) - mean*mean;
  float rstd = rsqrtf(fmaxf(var,0.f)+1e-12f);
  #pragma unroll
  for (int k3=0;k3<3;k3++){
    int col = lane*4 + k3*256;
    float o[4];
    #pragma unroll
    for (int t=0;t<4;t++) o[t] = (vals[k3*4+t]-mean)*rstd*gg[col+t] + bb[col+t];
    *(uint2*)&x[base+col] = fpack4(o);
  }
}

/* ---------------- row LayerNorm bf16->bf16 (wave per row) ---------------- */
__global__ __launch_bounds__(256) void ln_k(const u16* __restrict__ in, const float* __restrict__ gg,
    const float* __restrict__ bb, u16* __restrict__ out)
{
  int row = (int)((blockIdx.x*256u + threadIdx.x)>>6);
  int lane = threadIdx.x&63;
  size_t base = (size_t)row*H_;
  float vals[12]; float s=0.f, sq=0.f;
  #pragma unroll
  for (int k3=0;k3<3;k3++){
    int col = lane*4+k3*256;
    float v[4]; bf4u(*(const uint2*)&in[base+col], v);
    #pragma unroll
    for (int t=0;t<4;t++){ vals[k3*4+t]=v[t]; s+=v[t]; sq+=v[t]*v[t]; }
  }
  s=wredf(s); sq=wredf(sq);
  float mean=s*(1.f/H_);
  float var=sq*(1.f/H_)-mean*mean;
  float rstd=rsqrtf(fmaxf(var,0.f)+1e-12f);
  #pragma unroll
  for (int k3=0;k3<3;k3++){
    int col=lane*4+k3*256;
    float o[4];
    #pragma unroll
    for (int t=0;t<4;t++) o[t]=(vals[k3*4+t]-mean)*rstd*gg[col+t]+bb[col+t];
    *(uint2*)&out[base+col]=fpack4(o);
  }
}

/* ---------------- 3x3 attention, wave per (row n, head h); writes c over Q in place ---------- */
__global__ __launch_bounds__(256) void attn_k(const u16* Q, const u16* Kt, const u16* Vt, u16* O)
{
  int gw = (int)((blockIdx.x*256u + threadIdx.x)>>6);
  int lane = threadIdx.x&63;
  int n = gw/12, h = gw - n*12;
  int sp = n % SP1;
  size_t base = (size_t)n*3*H_ + h*64 + lane;
  float q[3],k[3],v[3];
  #pragma unroll
  for (int j=0;j<3;j++){
    q[j]=bf2f(Q[base+(size_t)j*H_]);
    k[j]=bf2f(Kt[base+(size_t)j*H_]);
    v[j]=bf2f(Vt[base+(size_t)j*H_]);
  }
  float sc[9];
  #pragma unroll
  for (int a=0;a<3;a++)
    #pragma unroll
    for (int b=0;b<3;b++) sc[a*3+b]=q[a]*k[b];
  #pragma unroll
  for (int o=32;o;o>>=1){
    #pragma unroll
    for (int t=0;t<9;t++) sc[t]+=__shfl_xor(sc[t],o,64);
  }
  /* mask is purely positional: prev valid iff 1<=sp<128, next valid iff sp<127 */
  float b0 = (sp>=1 && sp<S_) ? 0.f : -1e4f;
  float b2 = (sp<S_-1) ? 0.f : -1e4f;
  #pragma unroll
  for (int a=0;a<3;a++){
    float s0=sc[a*3+0]*0.125f+b0;
    float s1=sc[a*3+1]*0.125f;
    float s2=sc[a*3+2]*0.125f+b2;
    float mx=fmaxf(s0,fmaxf(s1,s2));
    float e0=expf(s0-mx), e1=expf(s1-mx), e2=expf(s2-mx);
    float cv=(e0*v[0]+e1*v[1]+e2*v[2])/(e0+e1+e2);
    O[base+(size_t)a*H_]=f2bf(cv);
  }
}

/* ---------------- bf16 MFMA GEMM: C[MxN] = A[MxK] * Bt[NxK]^T + bias (+epilogue) ----------
   128x128 tile, BK=32, 4 waves, global_load_lds(16B) staging, mfma 16x16x32 bf16.
   EPI: 0 plain, 1 +residual R, 2 gelu(exact), 3 gate: C = R * sigmoid(acc+bias) * mask(row) */
template<int EPI>
__global__ __launch_bounds__(256) void gemm_k(const u16* __restrict__ A, int lda,
    const u16* __restrict__ Bt, const float* __restrict__ bias,
    const u16* __restrict__ R, int ldr, u16* __restrict__ C, int ldc, int K)
{
  __shared__ u16 As[128*32];
  __shared__ u16 Bs[128*32];
  const int tid = threadIdx.x;
  const int wave = tid>>6, lane = tid&63;
  const int wm = (wave>>1)*64, wn = (wave&1)*64;
  const int fr = lane&15, kg = lane>>4;
  f32x4 acc[4][4];
  #pragma unroll
  for (int i=0;i<4;i++)
    #pragma unroll
    for (int j=0;j<4;j++) acc[i][j] = (f32x4){0.f,0.f,0.f,0.f};

  const int ldab = lda*2, ldbb = K*2;
  const char* Ab = (const char*)(A + (size_t)blockIdx.x*128*lda);
  const char* Bb = (const char*)(Bt + (size_t)blockIdx.y*128*K);
  char* AsB = (char*)As; char* BsB = (char*)Bs;
  /* staging slots: slot = 16B; slot s -> tile row s>>2, byte (s&3)*16; thread covers slots tid, tid+256 */
  const int s0r = tid>>2,       s0c = (tid&3)*16;
  const int s1r = s0r + 64,     s1c = s0c;
  const int wofs = wave*1024;

  for (int kt=0; kt<K; kt+=32){
    const int kb = kt*2;
    gload16(Ab + (size_t)s0r*ldab + kb + s0c, AsB + wofs);
    gload16(Ab + (size_t)s1r*ldab + kb + s1c, AsB + 4096 + wofs);
    gload16(Bb + (size_t)s0r*ldbb + kb + s0c, BsB + wofs);
    gload16(Bb + (size_t)s1r*ldbb + kb + s1c, BsB + 4096 + wofs);
    __syncthreads();
    s16x8 af[4], bfr[4];
    #pragma unroll
    for (int i=0;i<4;i++) af[i]  = *(const s16x8*)(AsB + (size_t)((wm+i*16+fr)*64 + kg*16));
    #pragma unroll
    for (int j=0;j<4;j++) bfr[j] = *(const s16x8*)(BsB + (size_t)((wn+j*16+fr)*64 + kg*16));
    #pragma unroll
    for (int i=0;i<4;i++)
      #pragma unroll
      for (int j=0;j<4;j++)
        acc[i][j] = __builtin_amdgcn_mfma_f32_16x16x32_bf16(af[i], bfr[j], acc[i][j], 0,0,0);
    __syncthreads();
  }

  /* C/D layout (HW-verified): col=lane&15, row=(lane>>4)*4+reg */
  const int gr0 = (int)blockIdx.x*128 + wm + (lane>>4)*4;
  const int gc0 = (int)blockIdx.y*128 + wn + fr;
  #pragma unroll
  for (int j=0;j<4;j++){
    const int col = gc0 + j*16;
    const float bc = bias[col];
    #pragma unroll
    for (int i=0;i<4;i++){
      #pragma unroll
      for (int r=0;r<4;r++){
        const int row = gr0 + i*16 + r;
        float v = acc[i][j][r] + bc;
        if (EPI==1) v += bf2f(R[(size_t)row*ldr + col]);
        if (EPI==2) v = 0.5f*v*(1.f+erff(v*0.70710678118654752f));
        if (EPI==3){
          float xv = bf2f(R[(size_t)row*ldr + col]);
          int nn = row/3, j3 = row - nn*3;
          int sp = nn % SP1;
          float mk = (j3==1) ? 1.f : ((j3==0) ? (((sp>=1)&&(sp<S_))?1.f:0.f) : ((sp<S_-1)?1.f:0.f));
          v = xv * (1.f/(1.f+expf(-v))) * mk;
        }
        C[(size_t)row*ldc + col] = f2bf(v);
      }
    }
  }
}

/* ---------------- combine neighbors + aux + final LN -> f32 out (wave per output row) ------- */
__global__ __launch_bounds__(256) void final_k(const u16* __restrict__ G, const int* __restrict__ tt,
    const float* __restrict__ pe2, const float* __restrict__ te2, const float* __restrict__ gg,
    const float* __restrict__ bb, float* __restrict__ out)
{
  int r = (int)((blockIdx.x*256u+threadIdx.x)>>6);
  int lane = threadIdx.x&63;
  int bi = r>>7, sp = r&127;
  int n = bi*SP1+sp;
  int t = tt[r];
  size_t g1 = ((size_t)n*3+1)*H_;
  size_t g0 = ((size_t)(n+1)*3+0)*H_;
  size_t g2 = (n>0) ? ((size_t)(n-1)*3+2)*H_ : 0;
  const float* p2 = pe2 + (size_t)sp*H_;
  const float* t2 = te2 + (size_t)t*H_;
  float vals[12]; float s=0.f, sq=0.f;
  #pragma unroll
  for (int k3=0;k3<3;k3++){
    int col=lane*4+k3*256;
    float a[4], b[4], c[4]={0.f,0.f,0.f,0.f};
    bf4u(*(const uint2*)&G[g1+col], a);
    bf4u(*(const uint2*)&G[g0+col], b);
    if (n>0) bf4u(*(const uint2*)&G[g2+col], c);
    #pragma unroll
    for (int q=0;q<4;q++){
      float v = a[q]+b[q]+c[q] + p2[col+q] + t2[col+q];
      vals[k3*4+q]=v; s+=v; sq+=v*v;
    }
  }
  s=wredf(s); sq=wredf(sq);
  float mean=s*(1.f/H_), var=sq*(1.f/H_)-mean*mean;
  float rstd=rsqrtf(fmaxf(var,0.f)+1e-12f);
  #pragma unroll
  for (int k3=0;k3<3;k3++){
    int col=lane*4+k3*256;
    float4 o;
    o.x=(vals[k3*4+0]-mean)*rstd*gg[col+0]+bb[col+0];
    o.y=(vals[k3*4+1]-mean)*rstd*gg[col+1]+bb[col+1];
    o.z=(vals[k3*4+2]-mean)*rstd*gg[col+2]+bb[col+2];
    o.w=(vals[k3*4+3]-mean)*rstd*gg[col+3]+bb[col+3];
    *(float4*)&out[(size_t)r*H_+col]=o;
  }
}

/* ================================ host ================================ */
extern "C" void kernel_launch(void* const* d_in, const int* in_sizes, int n_in,
                              void* d_out, int out_size, void* d_ws, size_t ws_size,
                              hipStream_t stream)
{
  (void)in_sizes; (void)n_in; (void)out_size;
  const int*   ids  = (const int*)d_in[0];
  const int*   tt   = (const int*)d_in[1];
  const float* wemb = (const float*)d_in[2];
  const float* pe3  = (const float*)d_in[3];
  const float* te   = (const float*)d_in[4];
  const float* elg  = (const float*)d_in[5];
  const float* elb  = (const float*)d_in[6];
  const float* Wq   = (const float*)d_in[7];
  const float* bq   = (const float*)d_in[8];
  const float* Wk   = (const float*)d_in[9];
  const float* bk   = (const float*)d_in[10];
  const float* Wv   = (const float*)d_in[11];
  const float* bv   = (const float*)d_in[12];
  const float* Wo   = (const float*)d_in[13];
  const float* bo   = (const float*)d_in[14];
  const float* l1g  = (const float*)d_in[15];
  const float* l1b  = (const float*)d_in[16];
  const float* W1   = (const float*)d_in[17];
  const float* b1   = (const float*)d_in[18];
  const float* W2   = (const float*)d_in[19];
  const float* b2   = (const float*)d_in[20];
  const float* l2g  = (const float*)d_in[21];
  const float* l2b  = (const float*)d_in[22];
  const float* Wg   = (const float*)d_in[23];
  const float* bg   = (const float*)d_in[24];
  const float* pe2  = (const float*)d_in[25];
  const float* te2  = (const float*)d_in[26];
  const float* ng   = (const float*)d_in[27];
  const float* nb   = (const float*)d_in[28];

  char* p = (char*)d_ws;
  auto alloc = [&](size_t bytes)->char*{
    char* r = p; p += (bytes + 255) & ~((size_t)255); return r;
  };
  const size_t HH = (size_t)H_*H_;
  u16* wtq = (u16*)alloc((size_t)L_*HH*2);
  u16* wtk = (u16*)alloc((size_t)L_*HH*2);
  u16* wtv = (u16*)alloc((size_t)L_*HH*2);
  u16* wto = (u16*)alloc((size_t)L_*HH*2);
  u16* wt1 = (u16*)alloc((size_t)L_*H_*FF_*2);
  u16* wt2 = (u16*)alloc((size_t)L_*H_*FF_*2);
  u16* wtg = (u16*)alloc(HH*2);
  u16* xb  = (u16*)alloc((size_t)MPAD*H_*2);
  u16* qb  = (u16*)alloc((size_t)MPAD*H_*2);
  u16* kbf = (u16*)alloc((size_t)MPAD*H_*2);
  u16* vbf = (u16*)alloc((size_t)MPAD*H_*2);
  /* FFN intermediate: strip-mined to fit remaining workspace */
  size_t used = (size_t)(p - (char*)d_ws);
  size_t avail = ws_size > used ? ws_size - used : 0;
  long long mrows = (long long)(avail / ((size_t)FF_*2));
  int strip = (int)((mrows/128)*128);
  if (strip > MPAD) strip = MPAD;
  if (strip < 128) strip = 128;
  u16* fbf = (u16*)alloc((size_t)strip*FF_*2);

  /* weights -> bf16 transposed (Bt layout: [N][K]) */
  {
    TP9 P;
    P.s[0]=Wq;     P.d[0]=wtq;
    P.s[1]=Wq+HH;  P.d[1]=wtq+HH;
    P.s[2]=Wk;     P.d[2]=wtk;
    P.s[3]=Wk+HH;  P.d[3]=wtk+HH;
    P.s[4]=Wv;     P.d[4]=wtv;
    P.s[5]=Wv+HH;  P.d[5]=wtv+HH;
    P.s[6]=Wo;     P.d[6]=wto;
    P.s[7]=Wo+HH;  P.d[7]=wto+HH;
    P.s[8]=Wg;     P.d[8]=wtg;
    tconv_k<<<dim3(H_/32, H_/32, 9), 256, 0, stream>>>(P, H_, H_);
  }
  {
    TP9 P; for (int i=0;i<9;i++){P.s[i]=Wq;P.d[i]=wtq;}
    P.s[0]=W1;                 P.d[0]=wt1;
    P.s[1]=W1+(size_t)H_*FF_;  P.d[1]=wt1+(size_t)H_*FF_;
    tconv_k<<<dim3(FF_/32, H_/32, 2), 256, 0, stream>>>(P, H_, FF_);
  }
  {
    TP9 P; for (int i=0;i<9;i++){P.s[i]=Wq;P.d[i]=wtq;}
    P.s[0]=W2;                 P.d[0]=wt2;
    P.s[1]=W2+(size_t)H_*FF_;  P.d[1]=wt2+(size_t)H_*FF_;
    tconv_k<<<dim3(H_/32, FF_/32, 2), 256, 0, stream>>>(P, FF_, H_);
  }

  embed_k<<<MPAD/4, 256, 0, stream>>>(ids, wemb, pe3, te, elg, elb, xb);

  for (int i=0;i<L_;i++){
    const u16* wq_i = wtq + (size_t)i*HH;
    const u16* wk_i = wtk + (size_t)i*HH;
    const u16* wv_i = wtv + (size_t)i*HH;
    const u16* wo_i = wto + (size_t)i*HH;
    const u16* w1_i = wt1 + (size_t)i*H_*FF_;
    const u16* w2_i = wt2 + (size_t)i*H_*FF_;
    gemm_k<0><<<dim3(MT_,6),256,0,stream>>>(xb, H_, wq_i, bq+(size_t)i*H_, (const u16*)0, 0, qb,  H_, H_);
    gemm_k<0><<<dim3(MT_,6),256,0,stream>>>(xb, H_, wk_i, bk+(size_t)i*H_, (const u16*)0, 0, kbf, H_, H_);
    gemm_k<0><<<dim3(MT_,6),256,0,stream>>>(xb, H_, wv_i, bv+(size_t)i*H_, (const u16*)0, 0, vbf, H_, H_);
    attn_k<<<(NROWS*12)/4, 256, 0, stream>>>(qb, kbf, vbf, qb);           /* c -> qb in place */
    gemm_k<1><<<dim3(MT_,6),256,0,stream>>>(qb, H_, wo_i, bo+(size_t)i*H_, xb, H_, kbf, H_, H_);
    ln_k<<<M_/4,256,0,stream>>>(kbf, l1g+(size_t)i*H_, l1b+(size_t)i*H_, xb);
    for (int s0=0; s0<MPAD; s0+=strip){
      int rows = MPAD - s0; if (rows > strip) rows = strip;
      gemm_k<2><<<dim3(rows/128,FF_/128),256,0,stream>>>(xb+(size_t)s0*H_, H_, w1_i, b1+(size_t)i*FF_,
                                                         (const u16*)0, 0, fbf, FF_, H_);
      gemm_k<1><<<dim3(rows/128,6),256,0,stream>>>(fbf, FF_, w2_i, b2+(size_t)i*H_,
                                                   xb+(size_t)s0*H_, H_, kbf+(size_t)s0*H_, H_, FF_);
    }
    ln_k<<<M_/4,256,0,stream>>>(kbf, l2g+(size_t)i*H_, l2b+(size_t)i*H_, xb);
  }
  /* gate: kbf = xb * sigmoid(xb@Wg + bg) * mask  (center_ok is a provable no-op on the output) */
  gemm_k<3><<<dim3(MT_,6),256,0,stream>>>(xb, H_, wtg, bg, xb, H_, kbf, H_, H_);
  final_k<<<(B_*S_)/4, 256, 0, stream>>>(kbf, tt, pe2, te2, ng, nb, (float*)d_out);
}

// Round 3
// 1738.872 us; speedup vs baseline: 1.1862x; 1.1862x over previous
//
#include <hip/hip_runtime.h>
#include <math.h>

typedef unsigned short u16;
typedef unsigned int   u32;

#define H_    768
#define FF_   3072
#define L_    2
#define B_    64
#define S_    128
#define SP1   129
#define NROWS (B_*SP1)     /* 8256  */
#define M_    (NROWS*3)    /* 24768 */
#define MPAD  24832        /* 194*128 */
#define MT_   (MPAD/128)   /* 194 */
#define QKV_N 2304

typedef __attribute__((ext_vector_type(8))) short s16x8;
typedef __attribute__((ext_vector_type(4))) float f32x4;

__device__ __forceinline__ float bf2f(u16 u){ union{u32 i; float f;} c; c.i=((u32)u)<<16; return c.f; }
__device__ __forceinline__ u16 f2bf(float x){ union{float f; u32 i;} c; c.f=x; u32 r=c.i+0x7fffu+((c.i>>16)&1u); return (u16)(r>>16); }

__device__ __forceinline__ void bf4u(uint2 u, float* v){
  v[0]=bf2f((u16)(u.x&0xffffu)); v[1]=bf2f((u16)(u.x>>16));
  v[2]=bf2f((u16)(u.y&0xffffu)); v[3]=bf2f((u16)(u.y>>16));
}
__device__ __forceinline__ uint2 fpack4(const float* v){
  u32 lo=(u32)f2bf(v[0]) | ((u32)f2bf(v[1])<<16);
  u32 hi=(u32)f2bf(v[2]) | ((u32)f2bf(v[3])<<16);
  return make_uint2(lo,hi);
}
__device__ __forceinline__ float wredf(float v){
  #pragma unroll
  for (int o=32;o;o>>=1) v += __shfl_xor(v,o,64);
  return v;
}

typedef const __attribute__((address_space(1))) void* gas1_t;
typedef __attribute__((address_space(3))) void*       las3_t;
__device__ __forceinline__ void gload16(const void* g, void* l){
  __builtin_amdgcn_global_load_lds((gas1_t)g, (las3_t)l, 16, 0, 0);
}

/* ---------------- weight transpose + f32->bf16 convert ---------------- */
struct TP9 { const float* s[9]; u16* d[9]; };

__global__ __launch_bounds__(256) void tconv_k(TP9 P, int Rr, int Cc){
  __shared__ u16 tle[32][33];
  const float* src = P.s[blockIdx.z];
  u16* dst = P.d[blockIdx.z];
  int c0 = blockIdx.x*32, r0 = blockIdx.y*32;
  int tx = threadIdx.x&31, ty = threadIdx.x>>5;
  #pragma unroll
  for (int i=0;i<32;i+=8) tle[ty+i][tx] = f2bf(src[(size_t)(r0+ty+i)*Cc + (c0+tx)]);
  __syncthreads();
  #pragma unroll
  for (int i=0;i<32;i+=8) dst[(size_t)(c0+ty+i)*Rr + (r0+tx)] = tle[tx][ty+i];
}

/* ---------------- bias concat: bqkv[L][2304] ---------------- */
__global__ __launch_bounds__(256) void bcat_k(const float* bq, const float* bk, const float* bv, float* dst){
  int i = (int)(blockIdx.x*256u + threadIdx.x);
  if (i >= L_*QKV_N) return;
  int l = i/QKV_N, c = i - l*QKV_N;
  float v = (c<H_) ? bq[l*H_+c] : (c<2*H_) ? bk[l*H_+c-H_] : bv[l*H_+c-2*H_];
  dst[i] = v;
}

/* ---------------- embedding gather + LN (wave per token row) ---------------- */
__global__ __launch_bounds__(256) void embed_k(const int* __restrict__ ids, const float* __restrict__ wemb,
    const float* __restrict__ pe3, const float* __restrict__ te, const float* __restrict__ gg,
    const float* __restrict__ bb, u16* __restrict__ x)
{
  int m = (int)((blockIdx.x*256u + threadIdx.x)>>6);
  int lane = threadIdx.x&63;
  size_t base = (size_t)m*H_;
  if (m >= M_){
    #pragma unroll
    for (int k3=0;k3<3;k3++){ int col=lane*4+k3*256; *(uint2*)&x[base+col]=make_uint2(0u,0u); }
    return;
  }
  int n = m/3, j = m - n*3;
  int bi = n/SP1, sp = n - bi*SP1;
  int id = 0;
  if (sp < S_){
    int s2 = sp + j - 1;
    if (s2 >= 0 && s2 < S_) id = ids[bi*S_ + s2];
  }
  const float* wr = wemb + (size_t)id*H_;
  const float* pr = pe3 + j*H_;
  float vals[12]; float s=0.f, sq=0.f;
  #pragma unroll
  for (int k3=0;k3<3;k3++){
    int col = lane*4 + k3*256;
    float4 wv = *(const float4*)(wr+col);
    float4 pv = *(const float4*)(pr+col);
    float4 tv = *(const float4*)(te+col);
    float a0=wv.x+pv.x+tv.x, a1=wv.y+pv.y+tv.y, a2=wv.z+pv.z+tv.z, a3=wv.w+pv.w+tv.w;
    vals[k3*4+0]=a0; vals[k3*4+1]=a1; vals[k3*4+2]=a2; vals[k3*4+3]=a3;
    s += a0+a1+a2+a3; sq += a0*a0+a1*a1+a2*a2+a3*a3;
  }
  s = wredf(s); sq = wredf(sq);
  float mean = s*(1.f/H_);
  float var  = sq*(1.f/H_) - mean*mean;
  float rstd = rsqrtf(fmaxf(var,0.f)+1e-12f);
  #pragma unroll
  for (int k3=0;k3<3;k3++){
    int col = lane*4 + k3*256;
    float o[4];
    #pragma unroll
    for (int t=0;t<4;t++) o[t] = (vals[k3*4+t]-mean)*rstd*gg[col+t] + bb[col+t];
    *(uint2*)&x[base+col] = fpack4(o);
  }
}

/* ---------------- row LayerNorm bf16->bf16 (wave per row) ---------------- */
__global__ __launch_bounds__(256) void ln_k(const u16* __restrict__ in, const float* __restrict__ gg,
    const float* __restrict__ bb, u16* __restrict__ out)
{
  int row = (int)((blockIdx.x*256u + threadIdx.x)>>6);
  int lane = threadIdx.x&63;
  size_t base = (size_t)row*H_;
  float vals[12]; float s=0.f, sq=0.f;
  #pragma unroll
  for (int k3=0;k3<3;k3++){
    int col = lane*4+k3*256;
    float v[4]; bf4u(*(const uint2*)&in[base+col], v);
    #pragma unroll
    for (int t=0;t<4;t++){ vals[k3*4+t]=v[t]; s+=v[t]; sq+=v[t]*v[t]; }
  }
  s=wredf(s); sq=wredf(sq);
  float mean=s*(1.f/H_);
  float var=sq*(1.f/H_)-mean*mean;
  float rstd=rsqrtf(fmaxf(var,0.f)+1e-12f);
  #pragma unroll
  for (int k3=0;k3<3;k3++){
    int col=lane*4+k3*256;
    float o[4];
    #pragma unroll
    for (int t=0;t<4;t++) o[t]=(vals[k3*4+t]-mean)*rstd*gg[col+t]+bb[col+t];
    *(uint2*)&out[base+col]=fpack4(o);
  }
}

/* ---------------- 3x3 attention on fused qkv buffer (stride 2304); c -> q slot in place ------ */
__global__ __launch_bounds__(256) void attn_k(u16* QKV)
{
  int gw = (int)((blockIdx.x*256u + threadIdx.x)>>6);
  int lane = threadIdx.x&63;
  int n = gw/12, h = gw - n*12;
  int sp = n % SP1;
  size_t base = (size_t)n*3*QKV_N + h*64 + lane;
  float q[3],k[3],v[3];
  #pragma unroll
  for (int j=0;j<3;j++){
    q[j]=bf2f(QKV[base+(size_t)j*QKV_N]);
    k[j]=bf2f(QKV[base+(size_t)j*QKV_N + H_]);
    v[j]=bf2f(QKV[base+(size_t)j*QKV_N + 2*H_]);
  }
  float sc[9];
  #pragma unroll
  for (int a=0;a<3;a++)
    #pragma unroll
    for (int b=0;b<3;b++) sc[a*3+b]=q[a]*k[b];
  #pragma unroll
  for (int o=32;o;o>>=1){
    #pragma unroll
    for (int t=0;t<9;t++) sc[t]+=__shfl_xor(sc[t],o,64);
  }
  float b0 = (sp>=1 && sp<S_) ? 0.f : -1e4f;
  float b2 = (sp<S_-1) ? 0.f : -1e4f;
  #pragma unroll
  for (int a=0;a<3;a++){
    float s0=sc[a*3+0]*0.125f+b0;
    float s1=sc[a*3+1]*0.125f;
    float s2=sc[a*3+2]*0.125f+b2;
    float mx=fmaxf(s0,fmaxf(s1,s2));
    float e0=expf(s0-mx), e1=expf(s1-mx), e2=expf(s2-mx);
    float cv=(e0*v[0]+e1*v[1]+e2*v[2])/(e0+e1+e2);
    QKV[base+(size_t)a*QKV_N]=f2bf(cv);
  }
}

/* ---------------- bf16 MFMA GEMM: C[MxN] = A[MxK] * Bt[NxK]^T + bias (+epilogue) ----------
   128x128 tile, BK=32, 4 waves, double-buffered LDS, ONE barrier per K-step (prefetch-first),
   bijective XCD-chunked swizzle with row-major tile order (A-strip L2/L3 reuse).
   EPI: 0 plain, 1 +residual R, 2 gelu(exact), 3 gate: C = R * sigmoid(acc+bias) * mask(row) */
template<int EPI>
__global__ __launch_bounds__(256,4) void gemm_k(const u16* __restrict__ A, int lda,
    const u16* __restrict__ Bt, const float* __restrict__ bias,
    const u16* __restrict__ R, int ldr, u16* __restrict__ C, int ldc, int K, int NT)
{
  __shared__ u16 As[2][4096];   /* [buf][128 rows * 32 cols] = 8KB each */
  __shared__ u16 Bs[2][4096];
  const int tid = threadIdx.x;
  const int wave = tid>>6, lane = tid&63;
  const int wm = (wave>>1)*64, wn = (wave&1)*64;
  const int fr = lane&15, kg = lane>>4;

  /* bijective XCD swizzle (m204) over linear block id, then row-major (by fastest) */
  const int nwg = (int)gridDim.x;
  const int qq = nwg>>3, rr = nwg&7;
  const int xcd = (int)blockIdx.x&7, idx = (int)blockIdx.x>>3;
  const int swz = (xcd<rr ? xcd*(qq+1) : rr*(qq+1) + (xcd-rr)*qq) + idx;
  const int bx = swz/NT, by = swz - bx*NT;

  f32x4 acc[4][4];
  #pragma unroll
  for (int i=0;i<4;i++)
    #pragma unroll
    for (int j=0;j<4;j++) acc[i][j] = (f32x4){0.f,0.f,0.f,0.f};

  const int ldab = lda*2, ldbb = K*2;
  const char* Ab = (const char*)(A + (size_t)bx*128*lda);
  const char* Bb = (const char*)(Bt + (size_t)by*128*K);
  /* staging: thread covers 16B slots (row tid>>2, byte (tid&3)*16) and (+64 rows) */
  const int s0r = tid>>2, s0c = (tid&3)*16;
  const int s1r = s0r + 64;
  const int wofs = wave*1024;

  auto stage = [&](int buf, int kt){
    const int kb = kt*64;
    char* ad = (char*)(&As[buf][0]) + wofs;
    char* bd = (char*)(&Bs[buf][0]) + wofs;
    gload16(Ab + (size_t)s0r*ldab + kb + s0c, ad);
    gload16(Ab + (size_t)s1r*ldab + kb + s0c, ad + 4096);
    gload16(Bb + (size_t)s0r*ldbb + kb + s0c, bd);
    gload16(Bb + (size_t)s1r*ldbb + kb + s0c, bd + 4096);
  };

  const int nt = K>>5;
  stage(0, 0);
  __syncthreads();               /* vmcnt(0) drain included by compiler */
  int cur = 0;
  for (int t=0; t<nt; ++t){
    if (t+1 < nt) stage(cur^1, t+1);      /* prefetch next tile while computing this one */
    const char* AsB = (const char*)(&As[cur][0]);
    const char* BsB = (const char*)(&Bs[cur][0]);
    s16x8 af[4], bfr[4];
    #pragma unroll
    for (int i=0;i<4;i++) af[i]  = *(const s16x8*)(AsB + ((wm+i*16+fr)<<6) + (kg<<4));
    #pragma unroll
    for (int j=0;j<4;j++) bfr[j] = *(const s16x8*)(BsB + ((wn+j*16+fr)<<6) + (kg<<4));
    __builtin_amdgcn_s_setprio(1);
    #pragma unroll
    for (int i=0;i<4;i++)
      #pragma unroll
      for (int j=0;j<4;j++)
        acc[i][j] = __builtin_amdgcn_mfma_f32_16x16x32_bf16(af[i], bfr[j], acc[i][j], 0,0,0);
    __builtin_amdgcn_s_setprio(0);
    __syncthreads();             /* one barrier per K-step: drains prefetch + guards buf reuse */
    cur ^= 1;
  }

  /* C/D layout (HW-verified): col=lane&15, row=(lane>>4)*4+reg */
  const int gr0 = bx*128 + wm + (lane>>4)*4;
  const int gc0 = by*128 + wn + fr;
  #pragma unroll
  for (int j=0;j<4;j++){
    const int col = gc0 + j*16;
    const float bc = bias[col];
    #pragma unroll
    for (int i=0;i<4;i++){
      #pragma unroll
      for (int r=0;r<4;r++){
        const int row = gr0 + i*16 + r;
        float v = acc[i][j][r] + bc;
        if (EPI==1) v += bf2f(R[(size_t)row*ldr + col]);
        if (EPI==2) v = 0.5f*v*(1.f+erff(v*0.70710678118654752f));
        if (EPI==3){
          float xv = bf2f(R[(size_t)row*ldr + col]);
          int nn = row/3, j3 = row - nn*3;
          int sp = nn % SP1;
          float mk = (j3==1) ? 1.f : ((j3==0) ? (((sp>=1)&&(sp<S_))?1.f:0.f) : ((sp<S_-1)?1.f:0.f));
          v = xv * (1.f/(1.f+expf(-v))) * mk;
        }
        C[(size_t)row*ldc + col] = f2bf(v);
      }
    }
  }
}

/* ---------------- combine neighbors + aux + final LN -> f32 out (wave per output row) ------- */
__global__ __launch_bounds__(256) void final_k(const u16* __restrict__ G, const int* __restrict__ tt,
    const float* __restrict__ pe2, const float* __restrict__ te2, const float* __restrict__ gg,
    const float* __restrict__ bb, float* __restrict__ out)
{
  int r = (int)((blockIdx.x*256u+threadIdx.x)>>6);
  int lane = threadIdx.x&63;
  int bi = r>>7, sp = r&127;
  int n = bi*SP1+sp;
  int t = tt[r];
  size_t g1 = ((size_t)n*3+1)*H_;
  size_t g0 = ((size_t)(n+1)*3+0)*H_;
  size_t g2 = (n>0) ? ((size_t)(n-1)*3+2)*H_ : 0;
  const float* p2 = pe2 + (size_t)sp*H_;
  const float* t2 = te2 + (size_t)t*H_;
  float vals[12]; float s=0.f, sq=0.f;
  #pragma unroll
  for (int k3=0;k3<3;k3++){
    int col=lane*4+k3*256;
    float a[4], b[4], c[4]={0.f,0.f,0.f,0.f};
    bf4u(*(const uint2*)&G[g1+col], a);
    bf4u(*(const uint2*)&G[g0+col], b);
    if (n>0) bf4u(*(const uint2*)&G[g2+col], c);
    #pragma unroll
    for (int q=0;q<4;q++){
      float v = a[q]+b[q]+c[q] + p2[col+q] + t2[col+q];
      vals[k3*4+q]=v; s+=v; sq+=v*v;
    }
  }
  s=wredf(s); sq=wredf(sq);
  float mean=s*(1.f/H_), var=sq*(1.f/H_)-mean*mean;
  float rstd=rsqrtf(fmaxf(var,0.f)+1e-12f);
  #pragma unroll
  for (int k3=0;k3<3;k3++){
    int col=lane*4+k3*256;
    float4 o;
    o.x=(vals[k3*4+0]-mean)*rstd*gg[col+0]+bb[col+0];
    o.y=(vals[k3*4+1]-mean)*rstd*gg[col+1]+bb[col+1];
    o.z=(vals[k3*4+2]-mean)*rstd*gg[col+2]+bb[col+2];
    o.w=(vals[k3*4+3]-mean)*rstd*gg[col+3]+bb[col+3];
    *(float4*)&out[(size_t)r*H_+col]=o;
  }
}

/* ================================ host ================================ */
extern "C" void kernel_launch(void* const* d_in, const int* in_sizes, int n_in,
                              void* d_out, int out_size, void* d_ws, size_t ws_size,
                              hipStream_t stream)
{
  (void)in_sizes; (void)n_in; (void)out_size;
  const int*   ids  = (const int*)d_in[0];
  const int*   tt   = (const int*)d_in[1];
  const float* wemb = (const float*)d_in[2];
  const float* pe3  = (const float*)d_in[3];
  const float* te   = (const float*)d_in[4];
  const float* elg  = (const float*)d_in[5];
  const float* elb  = (const float*)d_in[6];
  const float* Wq   = (const float*)d_in[7];
  const float* bq   = (const float*)d_in[8];
  const float* Wk   = (const float*)d_in[9];
  const float* bk   = (const float*)d_in[10];
  const float* Wv   = (const float*)d_in[11];
  const float* bv   = (const float*)d_in[12];
  const float* Wo   = (const float*)d_in[13];
  const float* bo   = (const float*)d_in[14];
  const float* l1g  = (const float*)d_in[15];
  const float* l1b  = (const float*)d_in[16];
  const float* W1   = (const float*)d_in[17];
  const float* b1   = (const float*)d_in[18];
  const float* W2   = (const float*)d_in[19];
  const float* b2   = (const float*)d_in[20];
  const float* l2g  = (const float*)d_in[21];
  const float* l2b  = (const float*)d_in[22];
  const float* Wg   = (const float*)d_in[23];
  const float* bg   = (const float*)d_in[24];
  const float* pe2  = (const float*)d_in[25];
  const float* te2  = (const float*)d_in[26];
  const float* ng   = (const float*)d_in[27];
  const float* nb   = (const float*)d_in[28];

  char* p = (char*)d_ws;
  auto alloc = [&](size_t bytes)->char*{
    char* r = p; p += (bytes + 255) & ~((size_t)255); return r;
  };
  const size_t HH = (size_t)H_*H_;
  u16*  wqkv = (u16*)alloc((size_t)L_*3*HH*2);       /* per layer: [2304][768] (q|k|v transposed) */
  u16*  wto  = (u16*)alloc((size_t)L_*HH*2);
  u16*  wt1  = (u16*)alloc((size_t)L_*H_*FF_*2);
  u16*  wt2  = (u16*)alloc((size_t)L_*H_*FF_*2);
  u16*  wtg  = (u16*)alloc(HH*2);
  float* bqkv= (float*)alloc((size_t)L_*QKV_N*4);
  u16*  xb   = (u16*)alloc((size_t)MPAD*H_*2);
  u16*  qkv  = (u16*)alloc((size_t)MPAD*QKV_N*2);
  u16*  kbf  = (u16*)alloc((size_t)MPAD*H_*2);
  size_t used = (size_t)(p - (char*)d_ws);
  size_t avail = ws_size > used ? ws_size - used : 0;
  long long mrows = (long long)(avail / ((size_t)FF_*2));
  int strip = (int)((mrows/128)*128);
  if (strip > MPAD) strip = MPAD;
  if (strip < 128) strip = 128;
  u16* fbf = (u16*)alloc((size_t)strip*FF_*2);

  /* weights -> bf16 transposed (Bt layout: [N][K]) */
  {
    TP9 P;
    P.s[0]=Wq;     P.d[0]=wqkv;            /* l0 q */
    P.s[1]=Wk;     P.d[1]=wqkv+HH;         /* l0 k */
    P.s[2]=Wv;     P.d[2]=wqkv+2*HH;       /* l0 v */
    P.s[3]=Wq+HH;  P.d[3]=wqkv+3*HH;       /* l1 q */
    P.s[4]=Wk+HH;  P.d[4]=wqkv+4*HH;       /* l1 k */
    P.s[5]=Wv+HH;  P.d[5]=wqkv+5*HH;       /* l1 v */
    P.s[6]=Wo;     P.d[6]=wto;
    P.s[7]=Wo+HH;  P.d[7]=wto+HH;
    P.s[8]=Wg;     P.d[8]=wtg;
    tconv_k<<<dim3(H_/32, H_/32, 9), 256, 0, stream>>>(P, H_, H_);
  }
  {
    TP9 P; for (int i=0;i<9;i++){P.s[i]=Wq;P.d[i]=wtg;}
    P.s[0]=W1;                 P.d[0]=wt1;
    P.s[1]=W1+(size_t)H_*FF_;  P.d[1]=wt1+(size_t)H_*FF_;
    tconv_k<<<dim3(FF_/32, H_/32, 2), 256, 0, stream>>>(P, H_, FF_);
  }
  {
    TP9 P; for (int i=0;i<9;i++){P.s[i]=Wq;P.d[i]=wtg;}
    P.s[0]=W2;                 P.d[0]=wt2;
    P.s[1]=W2+(size_t)H_*FF_;  P.d[1]=wt2+(size_t)H_*FF_;
    tconv_k<<<dim3(H_/32, FF_/32, 2), 256, 0, stream>>>(P, FF_, H_);
  }
  bcat_k<<<(L_*QKV_N+255)/256, 256, 0, stream>>>(bq, bk, bv, bqkv);

  embed_k<<<MPAD/4, 256, 0, stream>>>(ids, wemb, pe3, te, elg, elb, xb);

  for (int i=0;i<L_;i++){
    const u16* wqkv_i = wqkv + (size_t)i*3*HH;
    const u16* wo_i   = wto  + (size_t)i*HH;
    const u16* w1_i   = wt1  + (size_t)i*H_*FF_;
    const u16* w2_i   = wt2  + (size_t)i*H_*FF_;
    gemm_k<0><<<MT_*18,256,0,stream>>>(xb, H_, wqkv_i, bqkv+(size_t)i*QKV_N,
                                       (const u16*)0, 0, qkv, QKV_N, H_, 18);
    attn_k<<<(NROWS*12)/4, 256, 0, stream>>>(qkv);                 /* c -> q slot in place */
    gemm_k<1><<<MT_*6,256,0,stream>>>(qkv, QKV_N, wo_i, bo+(size_t)i*H_, xb, H_, kbf, H_, H_, 6);
    ln_k<<<M_/4,256,0,stream>>>(kbf, l1g+(size_t)i*H_, l1b+(size_t)i*H_, xb);
    for (int s0=0; s0<MPAD; s0+=strip){
      int rows = MPAD - s0; if (rows > strip) rows = strip;
      gemm_k<2><<<(rows/128)*24,256,0,stream>>>(xb+(size_t)s0*H_, H_, w1_i, b1+(size_t)i*FF_,
                                                (const u16*)0, 0, fbf, FF_, H_, 24);
      gemm_k<1><<<(rows/128)*6,256,0,stream>>>(fbf, FF_, w2_i, b2+(size_t)i*H_,
                                               xb+(size_t)s0*H_, H_, kbf+(size_t)s0*H_, H_, FF_, 6);
    }
    ln_k<<<M_/4,256,0,stream>>>(kbf, l2g+(size_t)i*H_, l2b+(size_t)i*H_, xb);
  }
  /* gate: kbf = xb * sigmoid(xb@Wg + bg) * mask */
  gemm_k<3><<<MT_*6,256,0,stream>>>(xb, H_, wtg, bg, xb, H_, kbf, H_, H_, 6);
  final_k<<<(B_*S_)/4, 256, 0, stream>>>(kbf, tt, pe2, te2, ng, nb, (float*)d_out);
}

// Round 7
// 1733.250 us; speedup vs baseline: 1.1900x; 1.0032x over previous
//
#include <hip/hip_runtime.h>
#include <math.h>

typedef unsigned short u16;
typedef unsigned int   u32;

#define H_    768
#define FF_   3072
#define L_    2
#define B_    64
#define S_    128
#define SP1   129
#define NROWS (B_*SP1)     /* 8256  */
#define M_    (NROWS*3)    /* 24768 */
#define MPAD  24832        /* 194*128 */
#define MT_   (MPAD/128)   /* 194 */
#define QKV_N 2304

typedef __attribute__((ext_vector_type(8))) short s16x8;
typedef __attribute__((ext_vector_type(4))) float f32x4;

__device__ __forceinline__ float bf2f(u16 u){ union{u32 i; float f;} c; c.i=((u32)u)<<16; return c.f; }
__device__ __forceinline__ u16 f2bf(float x){ union{float f; u32 i;} c; c.f=x; u32 r=c.i+0x7fffu+((c.i>>16)&1u); return (u16)(r>>16); }

__device__ __forceinline__ void bf4u(uint2 u, float* v){
  v[0]=bf2f((u16)(u.x&0xffffu)); v[1]=bf2f((u16)(u.x>>16));
  v[2]=bf2f((u16)(u.y&0xffffu)); v[3]=bf2f((u16)(u.y>>16));
}
__device__ __forceinline__ uint2 fpack4(const float* v){
  u32 lo=(u32)f2bf(v[0]) | ((u32)f2bf(v[1])<<16);
  u32 hi=(u32)f2bf(v[2]) | ((u32)f2bf(v[3])<<16);
  return make_uint2(lo,hi);
}
__device__ __forceinline__ float wredf(float v){
  #pragma unroll
  for (int o=32;o;o>>=1) v += __shfl_xor(v,o,64);
  return v;
}

typedef const __attribute__((address_space(1))) void* gas1_t;
typedef __attribute__((address_space(3))) void*       las3_t;
__device__ __forceinline__ void gload16(const void* g, void* l){
  __builtin_amdgcn_global_load_lds((gas1_t)g, (las3_t)l, 16, 0, 0);
}

/* ---------------- weight transpose + f32->bf16 convert ---------------- */
struct TP9 { const float* s[9]; u16* d[9]; };

__global__ __launch_bounds__(256) void tconv_k(TP9 P, int Rr, int Cc){
  __shared__ u16 tle[32][33];
  const float* src = P.s[blockIdx.z];
  u16* dst = P.d[blockIdx.z];
  int c0 = blockIdx.x*32, r0 = blockIdx.y*32;
  int tx = threadIdx.x&31, ty = threadIdx.x>>5;
  #pragma unroll
  for (int i=0;i<32;i+=8) tle[ty+i][tx] = f2bf(src[(size_t)(r0+ty+i)*Cc + (c0+tx)]);
  __syncthreads();
  #pragma unroll
  for (int i=0;i<32;i+=8) dst[(size_t)(c0+ty+i)*Rr + (r0+tx)] = tle[tx][ty+i];
}

/* ---------------- bias concat: bqkv[L][2304] ---------------- */
__global__ __launch_bounds__(256) void bcat_k(const float* bq, const float* bk, const float* bv, float* dst){
  int i = (int)(blockIdx.x*256u + threadIdx.x);
  if (i >= L_*QKV_N) return;
  int l = i/QKV_N, c = i - l*QKV_N;
  float v = (c<H_) ? bq[l*H_+c] : (c<2*H_) ? bk[l*H_+c-H_] : bv[l*H_+c-2*H_];
  dst[i] = v;
}

/* ---------------- embedding gather + LN (wave per token row) ---------------- */
__global__ __launch_bounds__(256) void embed_k(const int* __restrict__ ids, const float* __restrict__ wemb,
    const float* __restrict__ pe3, const float* __restrict__ te, const float* __restrict__ gg,
    const float* __restrict__ bb, u16* __restrict__ x)
{
  int m = (int)((blockIdx.x*256u + threadIdx.x)>>6);
  int lane = threadIdx.x&63;
  size_t base = (size_t)m*H_;
  if (m >= M_){
    #pragma unroll
    for (int k3=0;k3<3;k3++){ int col=lane*4+k3*256; *(uint2*)&x[base+col]=make_uint2(0u,0u); }
    return;
  }
  int n = m/3, j = m - n*3;
  int bi = n/SP1, sp = n - bi*SP1;
  int id = 0;
  if (sp < S_){
    int s2 = sp + j - 1;
    if (s2 >= 0 && s2 < S_) id = ids[bi*S_ + s2];
  }
  const float* wr = wemb + (size_t)id*H_;
  const float* pr = pe3 + j*H_;
  float vals[12]; float s=0.f, sq=0.f;
  #pragma unroll
  for (int k3=0;k3<3;k3++){
    int col = lane*4 + k3*256;
    float4 wv = *(const float4*)(wr+col);
    float4 pv = *(const float4*)(pr+col);
    float4 tv = *(const float4*)(te+col);
    float a0=wv.x+pv.x+tv.x, a1=wv.y+pv.y+tv.y, a2=wv.z+pv.z+tv.z, a3=wv.w+pv.w+tv.w;
    vals[k3*4+0]=a0; vals[k3*4+1]=a1; vals[k3*4+2]=a2; vals[k3*4+3]=a3;
    s += a0+a1+a2+a3; sq += a0*a0+a1*a1+a2*a2+a3*a3;
  }
  s = wredf(s); sq = wredf(sq);
  float mean = s*(1.f/H_);
  float var  = sq*(1.f/H_) - mean*mean;
  float rstd = rsqrtf(fmaxf(var,0.f)+1e-12f);
  #pragma unroll
  for (int k3=0;k3<3;k3++){
    int col = lane*4 + k3*256;
    float o[4];
    #pragma unroll
    for (int t=0;t<4;t++) o[t] = (vals[k3*4+t]-mean)*rstd*gg[col+t] + bb[col+t];
    *(uint2*)&x[base+col] = fpack4(o);
  }
}

/* ---------------- row LayerNorm bf16->bf16 (wave per row) ---------------- */
__global__ __launch_bounds__(256) void ln_k(const u16* __restrict__ in, const float* __restrict__ gg,
    const float* __restrict__ bb, u16* __restrict__ out)
{
  int row = (int)((blockIdx.x*256u + threadIdx.x)>>6);
  int lane = threadIdx.x&63;
  size_t base = (size_t)row*H_;
  float vals[12]; float s=0.f, sq=0.f;
  #pragma unroll
  for (int k3=0;k3<3;k3++){
    int col = lane*4+k3*256;
    float v[4]; bf4u(*(const uint2*)&in[base+col], v);
    #pragma unroll
    for (int t=0;t<4;t++){ vals[k3*4+t]=v[t]; s+=v[t]; sq+=v[t]*v[t]; }
  }
  s=wredf(s); sq=wredf(sq);
  float mean=s*(1.f/H_);
  float var=sq*(1.f/H_)-mean*mean;
  float rstd=rsqrtf(fmaxf(var,0.f)+1e-12f);
  #pragma unroll
  for (int k3=0;k3<3;k3++){
    int col=lane*4+k3*256;
    float o[4];
    #pragma unroll
    for (int t=0;t<4;t++) o[t]=(vals[k3*4+t]-mean)*rstd*gg[col+t]+bb[col+t];
    *(uint2*)&out[base+col]=fpack4(o);
  }
}

/* ---------------- 3x3 attention on fused qkv buffer (stride 2304); c -> q slot in place ------ */
__global__ __launch_bounds__(256) void attn_k(u16* QKV)
{
  int gw = (int)((blockIdx.x*256u + threadIdx.x)>>6);
  int lane = threadIdx.x&63;
  int n = gw/12, h = gw - n*12;
  int sp = n % SP1;
  size_t base = (size_t)n*3*QKV_N + h*64 + lane;
  float q[3],k[3],v[3];
  #pragma unroll
  for (int j=0;j<3;j++){
    q[j]=bf2f(QKV[base+(size_t)j*QKV_N]);
    k[j]=bf2f(QKV[base+(size_t)j*QKV_N + H_]);
    v[j]=bf2f(QKV[base+(size_t)j*QKV_N + 2*H_]);
  }
  float sc[9];
  #pragma unroll
  for (int a=0;a<3;a++)
    #pragma unroll
    for (int b=0;b<3;b++) sc[a*3+b]=q[a]*k[b];
  #pragma unroll
  for (int o=32;o;o>>=1){
    #pragma unroll
    for (int t=0;t<9;t++) sc[t]+=__shfl_xor(sc[t],o,64);
  }
  float b0 = (sp>=1 && sp<S_) ? 0.f : -1e4f;
  float b2 = (sp<S_-1) ? 0.f : -1e4f;
  #pragma unroll
  for (int a=0;a<3;a++){
    float s0=sc[a*3+0]*0.125f+b0;
    float s1=sc[a*3+1]*0.125f;
    float s2=sc[a*3+2]*0.125f+b2;
    float mx=fmaxf(s0,fmaxf(s1,s2));
    float e0=expf(s0-mx), e1=expf(s1-mx), e2=expf(s2-mx);
    float cv=(e0*v[0]+e1*v[1]+e2*v[2])/(e0+e1+e2);
    QKV[base+(size_t)a*QKV_N]=f2bf(cv);
  }
}

/* ---------------- bf16 MFMA GEMM: C[MxN] = A[MxK] * Bt[NxK]^T + bias (+epilogue) ----------
   128x128 tile, BK=32, 4 waves, double-buffered LDS, ONE barrier per K-step (prefetch-first),
   bijective XCD-chunked swizzle (row-major tile order), T2 LDS XOR-swizzle:
   LDS conceptual [128 rows][64B]; slot swizzle c' = c ^ (((row>>1)&3)<<4), applied on BOTH the
   pre-swizzled global source (LDS dest stays linear for global_load_lds) and the ds_read side.
   Rows 0..7 then cover all 32 banks -> fragment reads are 2-way (free) instead of 8-way.
   EPI: 0 plain, 1 +residual R, 2 gelu(exact), 3 gate: C = R * sigmoid(acc+bias) * mask(row) */
template<int EPI>
__global__ __launch_bounds__(256,4) void gemm_k(const u16* __restrict__ A, int lda,
    const u16* __restrict__ Bt, const float* __restrict__ bias,
    const u16* __restrict__ R, int ldr, u16* __restrict__ C, int ldc, int K, int NT)
{
  __shared__ u16 As[2][4096];   /* [buf][128 rows * 32 cols] = 8KB each */
  __shared__ u16 Bs[2][4096];
  const int tid = threadIdx.x;
  const int wave = tid>>6, lane = tid&63;
  const int wm = (wave>>1)*64, wn = (wave&1)*64;
  const int fr = lane&15, kg = lane>>4;

  /* bijective XCD swizzle (m204) over linear block id, then row-major (by fastest) */
  const int nwg = (int)gridDim.x;
  const int qq = nwg>>3, rr = nwg&7;
  const int xcd = (int)blockIdx.x&7, idx = (int)blockIdx.x>>3;
  const int swz = (xcd<rr ? xcd*(qq+1) : rr*(qq+1) + (xcd-rr)*qq) + idx;
  const int bx = swz/NT, by = swz - bx*NT;

  f32x4 acc[4][4];
  #pragma unroll
  for (int i=0;i<4;i++)
    #pragma unroll
    for (int j=0;j<4;j++) acc[i][j] = (f32x4){0.f,0.f,0.f,0.f};

  const int ldab = lda*2, ldbb = K*2;
  const char* Ab = (const char*)(A + (size_t)bx*128*lda);
  const char* Bb = (const char*)(Bt + (size_t)by*128*K);
  /* staging: thread covers 16B slots (row tid>>2, byte (tid&3)*16) and (+64 rows).
     Pre-swizzle the GLOBAL source column with the same involution the reader uses;
     swz(r) == swz(r+64) since only row bits [2:1] participate. */
  const int s0r = tid>>2;
  const int s1r = s0r + 64;
  const int c_sw = ((tid&3)*16) ^ (((s0r>>1)&3)<<4);
  const int wofs = wave*1024;

  auto stage = [&](int buf, int kt){
    const int kb = kt*64;
    char* ad = (char*)(&As[buf][0]) + wofs;
    char* bd = (char*)(&Bs[buf][0]) + wofs;
    gload16(Ab + (size_t)s0r*ldab + kb + c_sw, ad);
    gload16(Ab + (size_t)s1r*ldab + kb + c_sw, ad + 4096);
    gload16(Bb + (size_t)s0r*ldbb + kb + c_sw, bd);
    gload16(Bb + (size_t)s1r*ldbb + kb + c_sw, bd + 4096);
  };

  const int nt = K>>5;
  stage(0, 0);
  __syncthreads();               /* vmcnt(0) drain included by compiler */
  int cur = 0;
  for (int t=0; t<nt; ++t){
    if (t+1 < nt) stage(cur^1, t+1);      /* prefetch next tile while computing this one */
    const char* AsB = (const char*)(&As[cur][0]);
    const char* BsB = (const char*)(&Bs[cur][0]);
    s16x8 af[4], bfr[4];
    #pragma unroll
    for (int i=0;i<4;i++){
      const int ra = wm + i*16 + fr;
      af[i]  = *(const s16x8*)(AsB + (ra<<6) + ((kg<<4) ^ (((ra>>1)&3)<<4)));
    }
    #pragma unroll
    for (int j=0;j<4;j++){
      const int rb = wn + j*16 + fr;
      bfr[j] = *(const s16x8*)(BsB + (rb<<6) + ((kg<<4) ^ (((rb>>1)&3)<<4)));
    }
    __builtin_amdgcn_s_setprio(1);
    #pragma unroll
    for (int i=0;i<4;i++)
      #pragma unroll
      for (int j=0;j<4;j++)
        acc[i][j] = __builtin_amdgcn_mfma_f32_16x16x32_bf16(af[i], bfr[j], acc[i][j], 0,0,0);
    __builtin_amdgcn_s_setprio(0);
    __syncthreads();             /* one barrier per K-step: drains prefetch + guards buf reuse */
    cur ^= 1;
  }

  /* C/D layout (HW-verified): col=lane&15, row=(lane>>4)*4+reg */
  const int gr0 = bx*128 + wm + (lane>>4)*4;
  const int gc0 = by*128 + wn + fr;
  #pragma unroll
  for (int j=0;j<4;j++){
    const int col = gc0 + j*16;
    const float bc = bias[col];
    #pragma unroll
    for (int i=0;i<4;i++){
      #pragma unroll
      for (int r=0;r<4;r++){
        const int row = gr0 + i*16 + r;
        float v = acc[i][j][r] + bc;
        if (EPI==1) v += bf2f(R[(size_t)row*ldr + col]);
        if (EPI==2) v = 0.5f*v*(1.f+erff(v*0.70710678118654752f));
        if (EPI==3){
          float xv = bf2f(R[(size_t)row*ldr + col]);
          int nn = row/3, j3 = row - nn*3;
          int sp = nn % SP1;
          float mk = (j3==1) ? 1.f : ((j3==0) ? (((sp>=1)&&(sp<S_))?1.f:0.f) : ((sp<S_-1)?1.f:0.f));
          v = xv * (1.f/(1.f+expf(-v))) * mk;
        }
        C[(size_t)row*ldc + col] = f2bf(v);
      }
    }
  }
}

/* ---------------- combine neighbors + aux + final LN -> f32 out (wave per output row) ------- */
__global__ __launch_bounds__(256) void final_k(const u16* __restrict__ G, const int* __restrict__ tt,
    const float* __restrict__ pe2, const float* __restrict__ te2, const float* __restrict__ gg,
    const float* __restrict__ bb, float* __restrict__ out)
{
  int r = (int)((blockIdx.x*256u+threadIdx.x)>>6);
  int lane = threadIdx.x&63;
  int bi = r>>7, sp = r&127;
  int n = bi*SP1+sp;
  int t = tt[r];
  size_t g1 = ((size_t)n*3+1)*H_;
  size_t g0 = ((size_t)(n+1)*3+0)*H_;
  size_t g2 = (n>0) ? ((size_t)(n-1)*3+2)*H_ : 0;
  const float* p2 = pe2 + (size_t)sp*H_;
  const float* t2 = te2 + (size_t)t*H_;
  float vals[12]; float s=0.f, sq=0.f;
  #pragma unroll
  for (int k3=0;k3<3;k3++){
    int col=lane*4+k3*256;
    float a[4], b[4], c[4]={0.f,0.f,0.f,0.f};
    bf4u(*(const uint2*)&G[g1+col], a);
    bf4u(*(const uint2*)&G[g0+col], b);
    if (n>0) bf4u(*(const uint2*)&G[g2+col], c);
    #pragma unroll
    for (int q=0;q<4;q++){
      float v = a[q]+b[q]+c[q] + p2[col+q] + t2[col+q];
      vals[k3*4+q]=v; s+=v; sq+=v*v;
    }
  }
  s=wredf(s); sq=wredf(sq);
  float mean=s*(1.f/H_), var=sq*(1.f/H_)-mean*mean;
  float rstd=rsqrtf(fmaxf(var,0.f)+1e-12f);
  #pragma unroll
  for (int k3=0;k3<3;k3++){
    int col=lane*4+k3*256;
    float4 o;
    o.x=(vals[k3*4+0]-mean)*rstd*gg[col+0]+bb[col+0];
    o.y=(vals[k3*4+1]-mean)*rstd*gg[col+1]+bb[col+1];
    o.z=(vals[k3*4+2]-mean)*rstd*gg[col+2]+bb[col+2];
    o.w=(vals[k3*4+3]-mean)*rstd*gg[col+3]+bb[col+3];
    *(float4*)&out[(size_t)r*H_+col]=o;
  }
}

/* ================================ host ================================ */
extern "C" void kernel_launch(void* const* d_in, const int* in_sizes, int n_in,
                              void* d_out, int out_size, void* d_ws, size_t ws_size,
                              hipStream_t stream)
{
  (void)in_sizes; (void)n_in; (void)out_size;
  const int*   ids  = (const int*)d_in[0];
  const int*   tt   = (const int*)d_in[1];
  const float* wemb = (const float*)d_in[2];
  const float* pe3  = (const float*)d_in[3];
  const float* te   = (const float*)d_in[4];
  const float* elg  = (const float*)d_in[5];
  const float* elb  = (const float*)d_in[6];
  const float* Wq   = (const float*)d_in[7];
  const float* bq   = (const float*)d_in[8];
  const float* Wk   = (const float*)d_in[9];
  const float* bk   = (const float*)d_in[10];
  const float* Wv   = (const float*)d_in[11];
  const float* bv   = (const float*)d_in[12];
  const float* Wo   = (const float*)d_in[13];
  const float* bo   = (const float*)d_in[14];
  const float* l1g  = (const float*)d_in[15];
  const float* l1b  = (const float*)d_in[16];
  const float* W1   = (const float*)d_in[17];
  const float* b1   = (const float*)d_in[18];
  const float* W2   = (const float*)d_in[19];
  const float* b2   = (const float*)d_in[20];
  const float* l2g  = (const float*)d_in[21];
  const float* l2b  = (const float*)d_in[22];
  const float* Wg   = (const float*)d_in[23];
  const float* bg   = (const float*)d_in[24];
  const float* pe2  = (const float*)d_in[25];
  const float* te2  = (const float*)d_in[26];
  const float* ng   = (const float*)d_in[27];
  const float* nb   = (const float*)d_in[28];

  char* p = (char*)d_ws;
  auto alloc = [&](size_t bytes)->char*{
    char* r = p; p += (bytes + 255) & ~((size_t)255); return r;
  };
  const size_t HH = (size_t)H_*H_;
  u16*  wqkv = (u16*)alloc((size_t)L_*3*HH*2);       /* per layer: [2304][768] (q|k|v transposed) */
  u16*  wto  = (u16*)alloc((size_t)L_*HH*2);
  u16*  wt1  = (u16*)alloc((size_t)L_*H_*FF_*2);
  u16*  wt2  = (u16*)alloc((size_t)L_*H_*FF_*2);
  u16*  wtg  = (u16*)alloc(HH*2);
  float* bqkv= (float*)alloc((size_t)L_*QKV_N*4);
  u16*  xb   = (u16*)alloc((size_t)MPAD*H_*2);
  u16*  qkv  = (u16*)alloc((size_t)MPAD*QKV_N*2);
  u16*  kbf  = (u16*)alloc((size_t)MPAD*H_*2);
  size_t used = (size_t)(p - (char*)d_ws);
  size_t avail = ws_size > used ? ws_size - used : 0;
  long long mrows = (long long)(avail / ((size_t)FF_*2));
  int strip = (int)((mrows/128)*128);
  if (strip > MPAD) strip = MPAD;
  if (strip < 128) strip = 128;
  u16* fbf = (u16*)alloc((size_t)strip*FF_*2);

  /* weights -> bf16 transposed (Bt layout: [N][K]) */
  {
    TP9 P;
    P.s[0]=Wq;     P.d[0]=wqkv;            /* l0 q */
    P.s[1]=Wk;     P.d[1]=wqkv+HH;         /* l0 k */
    P.s[2]=Wv;     P.d[2]=wqkv+2*HH;       /* l0 v */
    P.s[3]=Wq+HH;  P.d[3]=wqkv+3*HH;       /* l1 q */
    P.s[4]=Wk+HH;  P.d[4]=wqkv+4*HH;       /* l1 k */
    P.s[5]=Wv+HH;  P.d[5]=wqkv+5*HH;       /* l1 v */
    P.s[6]=Wo;     P.d[6]=wto;
    P.s[7]=Wo+HH;  P.d[7]=wto+HH;
    P.s[8]=Wg;     P.d[8]=wtg;
    tconv_k<<<dim3(H_/32, H_/32, 9), 256, 0, stream>>>(P, H_, H_);
  }
  {
    TP9 P; for (int i=0;i<9;i++){P.s[i]=Wq;P.d[i]=wtg;}
    P.s[0]=W1;                 P.d[0]=wt1;
    P.s[1]=W1+(size_t)H_*FF_;  P.d[1]=wt1+(size_t)H_*FF_;
    tconv_k<<<dim3(FF_/32, H_/32, 2), 256, 0, stream>>>(P, H_, FF_);
  }
  {
    TP9 P; for (int i=0;i<9;i++){P.s[i]=Wq;P.d[i]=wtg;}
    P.s[0]=W2;                 P.d[0]=wt2;
    P.s[1]=W2+(size_t)H_*FF_;  P.d[1]=wt2+(size_t)H_*FF_;
    tconv_k<<<dim3(H_/32, FF_/32, 2), 256, 0, stream>>>(P, FF_, H_);
  }
  bcat_k<<<(L_*QKV_N+255)/256, 256, 0, stream>>>(bq, bk, bv, bqkv);

  embed_k<<<MPAD/4, 256, 0, stream>>>(ids, wemb, pe3, te, elg, elb, xb);

  for (int i=0;i<L_;i++){
    const u16* wqkv_i = wqkv + (size_t)i*3*HH;
    const u16* wo_i   = wto  + (size_t)i*HH;
    const u16* w1_i   = wt1  + (size_t)i*H_*FF_;
    const u16* w2_i   = wt2  + (size_t)i*H_*FF_;
    gemm_k<0><<<MT_*18,256,0,stream>>>(xb, H_, wqkv_i, bqkv+(size_t)i*QKV_N,
                                       (const u16*)0, 0, qkv, QKV_N, H_, 18);
    attn_k<<<(NROWS*12)/4, 256, 0, stream>>>(qkv);                 /* c -> q slot in place */
    gemm_k<1><<<MT_*6,256,0,stream>>>(qkv, QKV_N, wo_i, bo+(size_t)i*H_, xb, H_, kbf, H_, H_, 6);
    ln_k<<<M_/4,256,0,stream>>>(kbf, l1g+(size_t)i*H_, l1b+(size_t)i*H_, xb);
    for (int s0=0; s0<MPAD; s0+=strip){
      int rows = MPAD - s0; if (rows > strip) rows = strip;
      gemm_k<2><<<(rows/128)*24,256,0,stream>>>(xb+(size_t)s0*H_, H_, w1_i, b1+(size_t)i*FF_,
                                                (const u16*)0, 0, fbf, FF_, H_, 24);
      gemm_k<1><<<(rows/128)*6,256,0,stream>>>(fbf, FF_, w2_i, b2+(size_t)i*H_,
                                               xb+(size_t)s0*H_, H_, kbf+(size_t)s0*H_, H_, FF_, 6);
    }
    ln_k<<<M_/4,256,0,stream>>>(kbf, l2g+(size_t)i*H_, l2b+(size_t)i*H_, xb);
  }
  /* gate: kbf = xb * sigmoid(xb@Wg + bg) * mask */
  gemm_k<3><<<MT_*6,256,0,stream>>>(xb, H_, wtg, bg, xb, H_, kbf, H_, H_, 6);
  final_k<<<(B_*S_)/4, 256, 0, stream>>>(kbf, tt, pe2, te2, ng, nb, (float*)d_out);
}